// Round 3
// baseline (10417.690 us; speedup 1.0000x reference)
//
#include <hip/hip_runtime.h>
#include <cstdint>
#include <cstddef>

// ---------------------------------------------------------------------------
// Show-Attend-Tell decoder on MI355X (round 3).
// - Persistent cooperative kernel runs all 19 decode steps with internal
//   grid barriers (device-scope atomics + __threadfence per Guideline 16).
// - e_t @ w_ih[:512] precomputed for ALL steps upfront (eprec, bf16):
//   per-step gates K drops 3072 -> 2560, no e_t copies.
// - att1 GEMM XCD-chunked so both N-panels of an M-panel share an XCD L2.
// - y deferred to one GEMM after the loop (XCD-chunked).
// - Fallback: if cooperative launch fails, per-phase kernels per step.
// ---------------------------------------------------------------------------

#define DEV __device__ __forceinline__

typedef __attribute__((ext_vector_type(8))) short s16x8;
typedef __attribute__((ext_vector_type(4))) float f32x4;

constexpr int Bb = 128, Pp = 196, Dd = 2048, Aa = 512, Ee = 512, Hh = 512, Vv = 10000;
constexpr int Tt = 19, TMAX = 20;
constexpr int KXN = 2560;             // xin = [awe(2048), h(512)]
constexpr int NVP = 10048;

DEV float fbs(short s) {
    union { uint32_t u; float f; } v;
    v.u = ((uint32_t)(uint16_t)s) << 16;
    return v.f;
}
DEV short bfs(float f) {
    union { float f; uint32_t u; } v;
    v.f = f;
    uint32_t u = v.u;
    uint32_t r = (u + 0x7FFFu + ((u >> 16) & 1u)) >> 16;  // RNE
    return (short)(uint16_t)r;
}

// ---------------------------------------------------------------------------
// Grid barrier: sense-reversing, agent-scope atomics. bar[0]=count, bar[1]=gen.
// ---------------------------------------------------------------------------
DEV void grid_barrier(unsigned* bar, int nb) {
    __syncthreads();
    if (threadIdx.x == 0) {
        __threadfence();   // release this block's prior writes device-wide
        unsigned g = __hip_atomic_load(bar + 1, __ATOMIC_RELAXED, __HIP_MEMORY_SCOPE_AGENT);
        unsigned a = __hip_atomic_fetch_add(bar, 1u, __ATOMIC_ACQ_REL, __HIP_MEMORY_SCOPE_AGENT);
        if (a == (unsigned)nb - 1u) {
            __hip_atomic_store(bar, 0u, __ATOMIC_RELAXED, __HIP_MEMORY_SCOPE_AGENT);
            __hip_atomic_store(bar + 1, g + 1u, __ATOMIC_RELEASE, __HIP_MEMORY_SCOPE_AGENT);
        } else {
            while (__hip_atomic_load(bar + 1, __ATOMIC_ACQUIRE, __HIP_MEMORY_SCOPE_AGENT) == g)
                __builtin_amdgcn_s_sleep(2);
        }
        __threadfence();   // acquire
    }
    __syncthreads();
}

// ---------------------------------------------------------------------------
// 256-thread MFMA tile core: C[BM][BN] += A[m0..][K] * B[n0..][K]^T
// LDS XOR-swizzled (same expr on write & read).
// ---------------------------------------------------------------------------
template<int BM, int BN, int BK, int WR, int WC>
DEV void tile_mm(const short* __restrict__ Ag, int lda,
                 const short* __restrict__ Bg, int ldb, int K,
                 int m0, int n0, char* smem,
                 f32x4 (&acc)[(BM / WR) / 16][(BN / WC) / 16])
{
    constexpr int TH = 256;
    constexpr int NCH = BK / 8, AU = NCH * BM, BU = NCH * BN;
    constexpr int APT = AU / TH, BPT = BU / TH;
    constexpr int WM = BM / WR, WN = BN / WC, FM = WM / 16, FN = WN / 16;
    short* sA = (short*)smem;
    short* sB = (short*)smem + AU * 8;
    const int tid = threadIdx.x, lane = tid & 63, wid = tid >> 6;
    const int l15 = lane & 15, l4 = lane >> 4, wr = wid / WC, wc = wid % WC;

    #pragma unroll
    for (int i = 0; i < FM; ++i)
        #pragma unroll
        for (int j = 0; j < FN; ++j) acc[i][j] = {0.f, 0.f, 0.f, 0.f};

    for (int kt = 0; kt < K; kt += BK) {
        s16x8 ra[APT], rb[BPT];
        #pragma unroll
        for (int i = 0; i < APT; ++i) {
            int q2 = tid + TH * i;
            int r2 = q2 / NCH, ch = q2 % NCH;
            ra[i] = *(const s16x8*)(Ag + (size_t)(m0 + r2) * lda + kt + ch * 8);
        }
        #pragma unroll
        for (int i = 0; i < BPT; ++i) {
            int q2 = tid + TH * i;
            int r2 = q2 / NCH, ch = q2 % NCH;
            rb[i] = *(const s16x8*)(Bg + (size_t)(n0 + r2) * ldb + kt + ch * 8);
        }
        __syncthreads();
        #pragma unroll
        for (int i = 0; i < APT; ++i) {
            int q2 = tid + TH * i;
            int r2 = q2 / NCH, ch = q2 % NCH;
            *(s16x8*)(sA + (r2 * NCH + (ch ^ (r2 & 7))) * 8) = ra[i];
        }
        #pragma unroll
        for (int i = 0; i < BPT; ++i) {
            int q2 = tid + TH * i;
            int r2 = q2 / NCH, ch = q2 % NCH;
            *(s16x8*)(sB + (r2 * NCH + (ch ^ (r2 & 7))) * 8) = rb[i];
        }
        __syncthreads();
        #pragma unroll
        for (int ks = 0; ks < BK / 32; ++ks) {
            s16x8 af[FM], bf[FN];
            #pragma unroll
            for (int fm = 0; fm < FM; ++fm) {
                int rr2 = wr * WM + fm * 16 + l15, cc = ks * 4 + l4;
                af[fm] = *(const s16x8*)&sA[(rr2 * NCH + (cc ^ (rr2 & 7))) * 8];
            }
            #pragma unroll
            for (int fn = 0; fn < FN; ++fn) {
                int rr2 = wc * WN + fn * 16 + l15, cc = ks * 4 + l4;
                bf[fn] = *(const s16x8*)&sB[(rr2 * NCH + (cc ^ (rr2 & 7))) * 8];
            }
            #pragma unroll
            for (int fm = 0; fm < FM; ++fm)
                #pragma unroll
                for (int fn = 0; fn < FN; ++fn)
                    acc[fm][fn] = __builtin_amdgcn_mfma_f32_16x16x32_bf16(af[fm], bf[fn], acc[fm][fn], 0, 0, 0);
        }
    }
}

// ---------------------------------------------------------------------------
struct LoopArgs {
    const short* att1b; const short* catT; const short* combT;
    const short* eprec; const short* featb;
    const float* att_w; const float* att_b;
    const float* dec_b; const float* beta_b;
    const float* b_ih; const float* b_hh;
    float* att2b; float* gatebuf; float* alphaw;
    float* c_state; short* hnew_all;
    short* xin0; short* xin1;
    float* al_out; const int* lens;
    unsigned* bar;
};

// P1: att2 (f32 +dec_b) and gate (sigmoid +beta_b): h @ catT. 160 tasks.
DEV void phase1_task(const LoopArgs& a, const short* xc, int task, char* smem) {
    int m0 = (task & 3) * 32, n0 = (task >> 2) * 64;
    f32x4 acc[1][2];
    tile_mm<32, 64, 64, 2, 2>(xc + 2048, KXN, a.catT, 512, 512, m0, n0, smem, acc);
    int tid = threadIdx.x, lane = tid & 63, wid = tid >> 6;
    int l15 = lane & 15, l4 = lane >> 4, wr = wid / 2, wc = wid % 2;
    #pragma unroll
    for (int fn = 0; fn < 2; ++fn)
        #pragma unroll
        for (int r = 0; r < 4; ++r) {
            int m = m0 + wr * 16 + l4 * 4 + r;
            int n = n0 + wc * 32 + fn * 16 + l15;
            float v = acc[0][fn][r];
            if (n < 512) a.att2b[m * 512 + n] = v + a.dec_b[n];
            else a.gatebuf[m * 2048 + (n - 512)] = 1.f / (1.f + expf(-(v + a.beta_b[n - 512])));
        }
}

// P2: e = relu(att1+att2)@att_w + att_b, softmax, alpha. 128 tasks (b).
DEV void phase2_task(const LoopArgs& a, int b, int t, char* smem) {
    float* se = (float*)smem;        // 224 f32
    float* sred = se + 224;          // 256 f32
    int tid = threadIdx.x, lane = tid & 63, wid = tid >> 6;
    __syncthreads();
    float aw[8], a2[8];
    #pragma unroll
    for (int j = 0; j < 8; ++j) {
        aw[j] = a.att_w[lane * 8 + j];
        a2[j] = a.att2b[b * 512 + lane * 8 + j];
    }
    float ab = a.att_b[0];
    for (int p = wid; p < Pp; p += 4) {
        s16x8 row = *(const s16x8*)&a.att1b[((size_t)b * Pp + p) * 512 + lane * 8];
        float s = 0.f;
        #pragma unroll
        for (int j = 0; j < 8; ++j) {
            float v = fbs(row[j]) + a2[j];
            v = v > 0.f ? v : 0.f;
            s += v * aw[j];
        }
        #pragma unroll
        for (int m = 32; m; m >>= 1) s += __shfl_xor(s, m);
        if (lane == 0) se[p] = s + ab;
    }
    __syncthreads();
    float e = (tid < Pp) ? se[tid] : -3.0e38f;
    sred[tid] = e;
    __syncthreads();
    for (int st = 128; st > 0; st >>= 1) {
        if (tid < st) sred[tid] = fmaxf(sred[tid], sred[tid + st]);
        __syncthreads();
    }
    float mx = sred[0];
    __syncthreads();
    float ex = (tid < Pp) ? expf(e - mx) : 0.f;
    sred[tid] = ex;
    __syncthreads();
    for (int st = 128; st > 0; st >>= 1) {
        if (tid < st) sred[tid] += sred[tid + st];
        __syncthreads();
    }
    float inv = 1.f / sred[0];
    if (tid < Pp) {
        float al = ex * inv;
        a.alphaw[b * Pp + tid] = al;
        float mf = (t < a.lens[b] - 1) ? 1.f : 0.f;
        a.al_out[((size_t)b * Tt + t) * Pp + tid] = al * mf;
    }
    __syncthreads();
}

// P3: awe = gate * (alpha @ features) -> xc cols [0,2048). 512 tasks.
DEV void phase3_task(const LoopArgs& a, short* xc, int task, char* smem) {
    int b = task >> 2, ch = task & 3;
    float* sal = (float*)smem;
    int tid = threadIdx.x;
    __syncthreads();
    if (tid < Pp) sal[tid] = a.alphaw[b * Pp + tid];
    __syncthreads();
    int d0 = ch * 512 + tid * 2;
    const short* f = a.featb + (size_t)b * Pp * Dd + d0;
    float s0 = 0.f, s1 = 0.f;
    #pragma unroll 4
    for (int p = 0; p < Pp; ++p) {
        uint32_t v = *(const uint32_t*)(f + (size_t)p * Dd);
        float al = sal[p];
        s0 += al * fbs((short)(v & 0xFFFF));
        s1 += al * fbs((short)(v >> 16));
    }
    float2 g = *(const float2*)&a.gatebuf[b * 2048 + d0];
    uint32_t o = ((uint32_t)(uint16_t)bfs(g.y * s1) << 16) | (uint16_t)bfs(g.x * s0);
    *(uint32_t*)(xc + (size_t)b * KXN + d0) = o;
}

// P4: gates = xc @ combT (quad-permuted) + eprec + LSTM. 256 tasks.
DEV void phase4_task(const LoopArgs& a, const short* xc, short* xn, int t, int task, char* smem) {
    int m0 = (task & 3) * 32, n0 = (task >> 2) * 32;
    f32x4 acc[1][1];
    tile_mm<32, 32, 128, 2, 2>(xc, KXN, a.combT, KXN, KXN, m0, n0, smem, acc);
    int tid = threadIdx.x, lane = tid & 63, wid = tid >> 6;
    int l15 = lane & 15, l4 = lane >> 4, wr = wid / 2, wc = wid % 2;
    float* sE = (float*)smem;
    __syncthreads();
    #pragma unroll
    for (int r = 0; r < 4; ++r) {
        int ml = wr * 16 + l4 * 4 + r, nl = wc * 16 + l15;
        sE[ml * 32 + nl] = acc[0][0][r];
    }
    __syncthreads();
    int bl = tid >> 3, jl = tid & 7;
    int b = m0 + bl, q = (n0 >> 2) + jl;
    f32x4 ge = *(const f32x4*)&sE[bl * 32 + jl * 4];
    short4 ep = *(const short4*)&a.eprec[((size_t)t * 128 + b) * 2048 + n0 + jl * 4];
    float gi = ge[0] + fbs(ep.x) + a.b_ih[q]        + a.b_hh[q];
    float gf = ge[1] + fbs(ep.y) + a.b_ih[512 + q]  + a.b_hh[512 + q];
    float gg = ge[2] + fbs(ep.z) + a.b_ih[1024 + q] + a.b_hh[1024 + q];
    float go = ge[3] + fbs(ep.w) + a.b_ih[1536 + q] + a.b_hh[1536 + q];
    float si = 1.f / (1.f + expf(-gi));
    float sf = 1.f / (1.f + expf(-gf));
    float so = 1.f / (1.f + expf(-go));
    float tg = tanhf(gg);
    int sidx = b * 512 + q;
    float cn = sf * a.c_state[sidx] + si * tg;
    float hn = so * tanhf(cn);
    a.hnew_all[((size_t)t * 128 + b) * 512 + q] = bfs(hn);
    if (t < a.lens[b] - 1) {
        a.c_state[sidx] = cn;
        xn[(size_t)b * KXN + 2048 + q] = bfs(hn);
    }
}

// ---------------------------------------------------------------------------
// Persistent cooperative loop kernel.
// ---------------------------------------------------------------------------
__global__ __launch_bounds__(256, 2) void loop_k(LoopArgs a) {
    __shared__ __align__(16) char smem[16384];
    const int nb = (int)gridDim.x, bid = (int)blockIdx.x;
    for (int t = 0; t < Tt; ++t) {
        short* xc = (t & 1) ? a.xin1 : a.xin0;
        short* xn = (t & 1) ? a.xin0 : a.xin1;
        for (int task = bid; task < 160; task += nb) phase1_task(a, xc, task, smem);
        grid_barrier(a.bar, nb);
        for (int task = bid; task < 128; task += nb) phase2_task(a, task, t, smem);
        grid_barrier(a.bar, nb);
        for (int task = bid; task < 512; task += nb) phase3_task(a, xc, task, smem);
        grid_barrier(a.bar, nb);
        for (int task = bid; task < 256; task += nb) phase4_task(a, xc, xn, t, task, smem);
        grid_barrier(a.bar, nb);
    }
}

// Fallback per-phase kernels (if cooperative launch unavailable).
template<int PH>
__global__ __launch_bounds__(256, 2) void phase_k(LoopArgs a, int t) {
    __shared__ __align__(16) char smem[16384];
    short* xc = (t & 1) ? a.xin1 : a.xin0;
    short* xn = (t & 1) ? a.xin0 : a.xin1;
    if constexpr (PH == 1) {
        for (int task = blockIdx.x; task < 160; task += gridDim.x) phase1_task(a, xc, task, smem);
    } else if constexpr (PH == 2) {
        for (int task = blockIdx.x; task < 128; task += gridDim.x) phase2_task(a, task, t, smem);
    } else if constexpr (PH == 3) {
        for (int task = blockIdx.x; task < 512; task += gridDim.x) phase3_task(a, xc, task, smem);
    } else {
        for (int task = blockIdx.x; task < 256; task += gridDim.x) phase4_task(a, xc, xn, t, task, smem);
    }
}

// ---------------------------------------------------------------------------
// Standalone GEMM (precompute + y). B stored [N][K].
// EPI: 0 = bf16 out + bias, XCD-chunked 1-D grid (att1; 392 = 8*49 blocks)
//      1 = bf16 out, no bias (eprec)
//      3 = deferred y with mask (1-D XCD-chunked grid 157*19)
//      6 = h0c0: n<512 -> xin0 h-slot (+h_fc_b); else c_state (+c_fc_b)
// ---------------------------------------------------------------------------
template<int BM, int BN, int BK, int TH, int WR, int WC, int EPI>
__global__ __launch_bounds__(TH) void gemm_k(
    const short* __restrict__ Ag, int lda,
    const short* __restrict__ Bg, int ldb,
    int K,
    float* __restrict__ outF, float* __restrict__ outF2,
    short* __restrict__ outH, short* __restrict__ outH2,
    int ldo,
    const float* __restrict__ bias, const float* __restrict__ bias2,
    const int* __restrict__ lens)
{
    constexpr int NCH = BK / 8;
    constexpr int AU = NCH * BM, BU = NCH * BN;
    constexpr int APT = AU / TH, BPT = BU / TH;
    constexpr int WM = BM / WR, WN = BN / WC;
    constexpr int FM = WM / 16, FN = WN / 16;

    __shared__ __align__(16) short sA[AU * 8];
    __shared__ __align__(16) short sB[BU * 8];

    const int tid = threadIdx.x, lane = tid & 63, wid = tid >> 6;
    const int l15 = lane & 15, l4 = lane >> 4;

    int m0, n0, trow_ = 0;
    if constexpr (EPI == 0) {
        int task = (blockIdx.x & 7) * 49 + (blockIdx.x >> 3);   // 392 blocks
        m0 = (task >> 1) * BM;
        n0 = (task & 1) * BN;
    } else if constexpr (EPI == 3) {
        const int nwg = (int)gridDim.x;                         // 157*19
        const int qq = nwg >> 3, rr = nwg & 7;
        int xcd = (int)blockIdx.x & 7, idx = (int)blockIdx.x >> 3;
        int task = (xcd < rr) ? xcd * (qq + 1) + idx
                              : rr * (qq + 1) + (xcd - rr) * qq + idx;
        int npanel = task / Tt;
        trow_ = task - npanel * Tt;
        m0 = trow_ * BM;
        n0 = npanel * BN;
    } else {
        m0 = blockIdx.y * BM;
        n0 = blockIdx.x * BN;
    }
    const int wr = wid / WC, wc = wid % WC;

    f32x4 acc[FM][FN];
    #pragma unroll
    for (int i = 0; i < FM; ++i)
        #pragma unroll
        for (int j = 0; j < FN; ++j) acc[i][j] = {0.f, 0.f, 0.f, 0.f};

    for (int kt = 0; kt < K; kt += BK) {
        s16x8 ra[APT], rb[BPT];
        #pragma unroll
        for (int i = 0; i < APT; ++i) {
            int q2 = tid + TH * i;
            int r2 = q2 / NCH, ch = q2 % NCH;
            ra[i] = *(const s16x8*)(Ag + (size_t)(m0 + r2) * lda + kt + ch * 8);
        }
        #pragma unroll
        for (int i = 0; i < BPT; ++i) {
            int q2 = tid + TH * i;
            int r2 = q2 / NCH, ch = q2 % NCH;
            rb[i] = *(const s16x8*)(Bg + (size_t)(n0 + r2) * ldb + kt + ch * 8);
        }
        __syncthreads();
        #pragma unroll
        for (int i = 0; i < APT; ++i) {
            int q2 = tid + TH * i;
            int r2 = q2 / NCH, ch = q2 % NCH;
            *(s16x8*)(sA + (r2 * NCH + (ch ^ (r2 & 7))) * 8) = ra[i];
        }
        #pragma unroll
        for (int i = 0; i < BPT; ++i) {
            int q2 = tid + TH * i;
            int r2 = q2 / NCH, ch = q2 % NCH;
            *(s16x8*)(sB + (r2 * NCH + (ch ^ (r2 & 7))) * 8) = rb[i];
        }
        __syncthreads();
        #pragma unroll
        for (int ks = 0; ks < BK / 32; ++ks) {
            s16x8 af[FM], bf[FN];
            #pragma unroll
            for (int fm = 0; fm < FM; ++fm) {
                int rr2 = wr * WM + fm * 16 + l15, cc = ks * 4 + l4;
                af[fm] = *(const s16x8*)&sA[(rr2 * NCH + (cc ^ (rr2 & 7))) * 8];
            }
            #pragma unroll
            for (int fn = 0; fn < FN; ++fn) {
                int rr2 = wc * WN + fn * 16 + l15, cc = ks * 4 + l4;
                bf[fn] = *(const s16x8*)&sB[(rr2 * NCH + (cc ^ (rr2 & 7))) * 8];
            }
            #pragma unroll
            for (int fm = 0; fm < FM; ++fm)
                #pragma unroll
                for (int fn = 0; fn < FN; ++fn)
                    acc[fm][fn] = __builtin_amdgcn_mfma_f32_16x16x32_bf16(af[fm], bf[fn], acc[fm][fn], 0, 0, 0);
        }
    }

    #pragma unroll
    for (int fm = 0; fm < FM; ++fm)
        #pragma unroll
        for (int fn = 0; fn < FN; ++fn)
            #pragma unroll
            for (int r2 = 0; r2 < 4; ++r2) {
                int ml = wr * WM + fm * 16 + l4 * 4 + r2;
                int nl = wc * WN + fn * 16 + l15;
                int m = m0 + ml, n = n0 + nl;
                float v = acc[fm][fn][r2];
                if constexpr (EPI == 0) {
                    outH[(size_t)m * ldo + n] = bfs(v + bias[n]);
                } else if constexpr (EPI == 1) {
                    outH[(size_t)m * ldo + n] = bfs(v);
                } else if constexpr (EPI == 3) {
                    if (n < Vv) {
                        bool mk = trow_ < lens[ml] - 1;
                        outF[((size_t)ml * Tt + trow_) * Vv + n] = mk ? (v + bias[n]) : 0.f;
                    }
                } else if constexpr (EPI == 6) {
                    if (n < 512) {
                        outH2[(size_t)m * KXN + 2048 + n] = bfs(v + bias[n]);
                    } else {
                        outF2[(size_t)m * 512 + (n - 512)] = v + bias2[n - 512];
                    }
                }
            }
}

// ---------------------------------------------------------------------------
__global__ __launch_bounds__(256) void conv_mean_k(
    const float* __restrict__ feat, short* __restrict__ featb, short* __restrict__ meanb)
{
    int b = blockIdx.y;
    int d = (blockIdx.x * 256 + threadIdx.x) * 4;
    const float* f = feat + (size_t)b * Pp * Dd + d;
    short* o = featb + (size_t)b * Pp * Dd + d;
    float s0 = 0.f, s1 = 0.f, s2 = 0.f, s3 = 0.f;
    for (int p = 0; p < Pp; ++p) {
        float4 v = *(const float4*)(f + (size_t)p * Dd);
        s0 += v.x; s1 += v.y; s2 += v.z; s3 += v.w;
        short4 ov = make_short4(bfs(v.x), bfs(v.y), bfs(v.z), bfs(v.w));
        *(short4*)(o + (size_t)p * Dd) = ov;
    }
    const float inv = 1.f / 196.f;
    short4 mv = make_short4(bfs(s0 * inv), bfs(s1 * inv), bfs(s2 * inv), bfs(s3 * inv));
    *(short4*)(meanb + (size_t)b * Dd + d) = mv;
}

// fp32 [R][C] -> bf16 [perm(c)][dstStride] transpose (+zero pad).
// PERM=1: dst row = (c%512)*4 + c/512 (quad-permuted gate layout, C==2048).
template<int PERM>
__global__ __launch_bounds__(256) void transpose_bf16(
    const float* __restrict__ src, int R, int C,
    short* __restrict__ dst, int dstStride, int colOff, int Cpad)
{
    __shared__ float tile[32][33];
    int c0 = blockIdx.x * 32, r0 = blockIdx.y * 32;
    int tx = threadIdx.x & 31, ty = threadIdx.x >> 5;
    #pragma unroll
    for (int i = 0; i < 4; ++i) {
        int r = r0 + ty + i * 8, c = c0 + tx;
        tile[ty + i * 8][tx] = (r < R && c < C) ? src[(size_t)r * C + c] : 0.f;
    }
    __syncthreads();
    #pragma unroll
    for (int i = 0; i < 4; ++i) {
        int cc = c0 + ty + i * 8, rr = r0 + tx;
        if (cc < Cpad && rr < R) {
            int drow = PERM ? ((cc & 511) * 4 + (cc >> 9)) : cc;
            dst[(size_t)drow * dstStride + colOff + rr] = bfs(tile[tx][ty + i * 8]);
        }
    }
}

__global__ __launch_bounds__(256) void embg_k(
    const float* __restrict__ emb, const int* __restrict__ caps, short* __restrict__ embseq)
{
    size_t i = (size_t)blockIdx.x * 256 + threadIdx.x;
    if (i >= (size_t)Tt * Bb * Ee) return;
    int e = (int)(i % Ee);
    size_t r = i / Ee;
    int b = (int)(r % Bb);
    int t = (int)(r / Bb);
    int cap = caps[b * TMAX + t];
    embseq[i] = bfs(emb[(size_t)cap * Ee + e]);
}

// ---------------------------------------------------------------------------
extern "C" void kernel_launch(void* const* d_in, const int* in_sizes, int n_in,
                              void* d_out, int out_size, void* d_ws, size_t ws_size,
                              hipStream_t stream)
{
    const float* features = (const float*)d_in[0];
    const int* captions   = (const int*)d_in[1];
    const int* lengths    = (const int*)d_in[2];
    const float* emb      = (const float*)d_in[3];
    const float* h_fc_w   = (const float*)d_in[4];
    const float* h_fc_b   = (const float*)d_in[5];
    const float* c_fc_w   = (const float*)d_in[6];
    const float* c_fc_b   = (const float*)d_in[7];
    const float* enc_w    = (const float*)d_in[8];
    const float* enc_b    = (const float*)d_in[9];
    const float* dec_w    = (const float*)d_in[10];
    const float* dec_b    = (const float*)d_in[11];
    const float* att_w    = (const float*)d_in[12];
    const float* att_b    = (const float*)d_in[13];
    const float* beta_w   = (const float*)d_in[14];
    const float* beta_b   = (const float*)d_in[15];
    const float* w_ih     = (const float*)d_in[16];
    const float* b_ih     = (const float*)d_in[17];
    const float* w_hh     = (const float*)d_in[18];
    const float* b_hh     = (const float*)d_in[19];
    const float* cls_w    = (const float*)d_in[20];
    const float* cls_b    = (const float*)d_in[21];

    char* w = (char*)d_ws;
    auto alloc = [&](size_t bytes) {
        char* p = w;
        w += (bytes + 255) & ~(size_t)255;
        return p;
    };
    short* featb    = (short*)alloc((size_t)Bb * Pp * Dd * 2);
    short* att1b    = (short*)alloc((size_t)Bb * Pp * Aa * 2);
    short* encT     = (short*)alloc((size_t)Aa * Dd * 2);
    short* combT    = (short*)alloc((size_t)2048 * KXN * 2);   // quad-perm rows
    short* wtopT    = (short*)alloc((size_t)2048 * 512 * 2);   // quad-perm rows
    short* clsT     = (short*)alloc((size_t)NVP * Hh * 2);
    short* catT     = (short*)alloc((size_t)2560 * Hh * 2);    // [dec;beta]
    short* hcT      = (short*)alloc((size_t)1024 * Dd * 2);    // [h_fc;c_fc]
    short* embseq   = (short*)alloc((size_t)Tt * Bb * Ee * 2);
    short* meanb    = (short*)alloc((size_t)Bb * Dd * 2);
    short* eprec    = (short*)alloc((size_t)Tt * Bb * 2048 * 2);
    float* c_state  = (float*)alloc((size_t)Bb * Hh * 4);
    float* att2b    = (float*)alloc((size_t)Bb * Aa * 4);
    float* alphaw   = (float*)alloc((size_t)Bb * Pp * 4);
    float* gatebuf  = (float*)alloc((size_t)Bb * Dd * 4);
    short* xin0     = (short*)alloc((size_t)Bb * KXN * 2);
    short* xin1     = (short*)alloc((size_t)Bb * KXN * 2);
    short* hnew_all = (short*)alloc((size_t)Tt * Bb * Hh * 2);
    unsigned* bar   = (unsigned*)alloc(256);

    float* y_out  = (float*)d_out;
    float* al_out = y_out + (size_t)Bb * Tt * Vv;

    // ---- precompute ----
    hipMemsetAsync(bar, 0, 8, stream);
    conv_mean_k<<<dim3(2, 128), 256, 0, stream>>>(features, featb, meanb);
    transpose_bf16<0><<<dim3(16, 64), 256, 0, stream>>>(enc_w, 2048, 512, encT, 2048, 0, 512);
    transpose_bf16<0><<<dim3(16, 64), 256, 0, stream>>>(h_fc_w, 2048, 512, hcT, 2048, 0, 512);
    transpose_bf16<0><<<dim3(16, 64), 256, 0, stream>>>(c_fc_w, 2048, 512, hcT + (size_t)512 * 2048, 2048, 0, 512);
    transpose_bf16<0><<<dim3(16, 16), 256, 0, stream>>>(dec_w, 512, 512, catT, 512, 0, 512);
    transpose_bf16<0><<<dim3(64, 16), 256, 0, stream>>>(beta_w, 512, 2048, catT + (size_t)512 * 512, 512, 0, 2048);
    transpose_bf16<1><<<dim3(64, 64), 256, 0, stream>>>(w_ih + (size_t)512 * 2048, 2048, 2048, combT, KXN, 0, 2048);
    transpose_bf16<1><<<dim3(64, 16), 256, 0, stream>>>(w_hh, 512, 2048, combT, KXN, 2048, 2048);
    transpose_bf16<1><<<dim3(64, 16), 256, 0, stream>>>(w_ih, 512, 2048, wtopT, 512, 0, 2048);
    transpose_bf16<0><<<dim3(314, 16), 256, 0, stream>>>(cls_w, 512, 10000, clsT, 512, 0, NVP);
    embg_k<<<(Tt * Bb * Ee + 255) / 256, 256, 0, stream>>>(emb, captions, embseq);

    // h0/c0 GEMM: meanb @ hcT^T (EPI 6)
    gemm_k<128, 64, 64, 256, 2, 2, 6><<<dim3(16, 1), 256, 0, stream>>>(
        meanb, 2048, hcT, 2048, 2048,
        nullptr, c_state, nullptr, xin0, 0, h_fc_b, c_fc_b, nullptr);

    // att1 = features @ enc_w + enc_b (bf16), XCD-chunked 392-block grid
    gemm_k<128, 256, 64, 512, 2, 4, 0><<<dim3(392), 512, 0, stream>>>(
        featb, 2048, encT, 2048, 2048,
        nullptr, nullptr, att1b, nullptr, Aa, enc_b, nullptr, nullptr);

    // eprec = embseq @ wtopT^T (bf16, quad-permuted cols), all 19 steps
    gemm_k<128, 64, 64, 256, 2, 2, 1><<<dim3(32, 19), 256, 0, stream>>>(
        embseq, 512, wtopT, 512, 512,
        nullptr, nullptr, eprec, nullptr, 2048, nullptr, nullptr, nullptr);

    // ---- persistent cooperative decode loop ----
    LoopArgs args = {
        att1b, catT, combT, eprec, featb,
        att_w, att_b, dec_b, beta_b, b_ih, b_hh,
        att2b, gatebuf, alphaw, c_state, hnew_all,
        xin0, xin1, al_out, lengths, bar
    };
    void* kp[] = { (void*)&args };
    hipError_t cerr = hipLaunchCooperativeKernel((const void*)loop_k, dim3(512), dim3(256), kp, 0, stream);
    if (cerr != hipSuccess) {
        (void)hipGetLastError();
        cerr = hipLaunchCooperativeKernel((const void*)loop_k, dim3(256), dim3(256), kp, 0, stream);
    }
    if (cerr != hipSuccess) {
        (void)hipGetLastError();
        for (int t = 0; t < Tt; ++t) {
            phase_k<1><<<160, 256, 0, stream>>>(args, t);
            phase_k<2><<<128, 256, 0, stream>>>(args, t);
            phase_k<3><<<512, 256, 0, stream>>>(args, t);
            phase_k<4><<<256, 256, 0, stream>>>(args, t);
        }
    }

    // deferred y: hnew_all[2432][512] @ clsT^T, XCD-chunked
    gemm_k<128, 64, 64, 256, 2, 2, 3><<<dim3(157 * Tt), 256, 0, stream>>>(
        hnew_all, 512, clsT, 512, 512,
        y_out, nullptr, nullptr, nullptr, 0, cls_b, nullptr, lengths);
}

// Round 4
// 1474.857 us; speedup vs baseline: 7.0635x; 7.0635x over previous
//
#include <hip/hip_runtime.h>
#include <cstdint>
#include <cstddef>

// ---------------------------------------------------------------------------
// Show-Attend-Tell decoder on MI355X (round 4).
// Multi-launch (round-2 structure), 3 launches per decode step:
//   K1 att2+gate GEMM (160 blk) -> K2 fused e/softmax/awe (256 blk)
//   -> K3 gates GEMM K=2560 + fused LSTM epilogue (256 blk).
// Precompute: conv/mean, transposes, embseq, eprec = e_t @ w_ih (all steps),
// h0/c0 GEMM, att1 GEMM (XCD-chunked). y deferred to one GEMM at the end.
// NOTE (round-3 post-mortem): persistent coop kernel with agent-scope
// acquire-spin grid barrier = ~125us/barrier + cache-invalidate storms
// (1.7GB refetch). Do NOT revisit without a per-XCD hierarchical barrier.
// ---------------------------------------------------------------------------

#define DEV __device__ __forceinline__

typedef __attribute__((ext_vector_type(8))) short s16x8;
typedef __attribute__((ext_vector_type(4))) float f32x4;

constexpr int Bb = 128, Pp = 196, Dd = 2048, Aa = 512, Ee = 512, Hh = 512, Vv = 10000;
constexpr int Tt = 19, TMAX = 20;
constexpr int KXN = 2560;             // xin = [awe(2048), h(512)]
constexpr int NVP = 10048;

DEV float fbs(short s) {
    union { uint32_t u; float f; } v;
    v.u = ((uint32_t)(uint16_t)s) << 16;
    return v.f;
}
DEV short bfs(float f) {
    union { float f; uint32_t u; } v;
    v.f = f;
    uint32_t u = v.u;
    uint32_t r = (u + 0x7FFFu + ((u >> 16) & 1u)) >> 16;  // RNE
    return (short)(uint16_t)r;
}

// ---------------------------------------------------------------------------
// 256-thread MFMA tile core: C[BM][BN] += A[m0..][K] * B[n0..][K]^T
// LDS XOR-swizzled (same expr on write & read -> conflict-free, math-same).
// ---------------------------------------------------------------------------
template<int BM, int BN, int BK, int WR, int WC>
DEV void tile_mm(const short* __restrict__ Ag, int lda,
                 const short* __restrict__ Bg, int ldb, int K,
                 int m0, int n0, char* smem,
                 f32x4 (&acc)[(BM / WR) / 16][(BN / WC) / 16])
{
    constexpr int TH = 256;
    constexpr int NCH = BK / 8, AU = NCH * BM, BU = NCH * BN;
    constexpr int APT = AU / TH, BPT = BU / TH;
    constexpr int WM = BM / WR, WN = BN / WC, FM = WM / 16, FN = WN / 16;
    short* sA = (short*)smem;
    short* sB = (short*)smem + AU * 8;
    const int tid = threadIdx.x, lane = tid & 63, wid = tid >> 6;
    const int l15 = lane & 15, l4 = lane >> 4, wr = wid / WC, wc = wid % WC;

    #pragma unroll
    for (int i = 0; i < FM; ++i)
        #pragma unroll
        for (int j = 0; j < FN; ++j) acc[i][j] = {0.f, 0.f, 0.f, 0.f};

    for (int kt = 0; kt < K; kt += BK) {
        s16x8 ra[APT], rb[BPT];
        #pragma unroll
        for (int i = 0; i < APT; ++i) {
            int q2 = tid + TH * i;
            int r2 = q2 / NCH, ch = q2 % NCH;
            ra[i] = *(const s16x8*)(Ag + (size_t)(m0 + r2) * lda + kt + ch * 8);
        }
        #pragma unroll
        for (int i = 0; i < BPT; ++i) {
            int q2 = tid + TH * i;
            int r2 = q2 / NCH, ch = q2 % NCH;
            rb[i] = *(const s16x8*)(Bg + (size_t)(n0 + r2) * ldb + kt + ch * 8);
        }
        __syncthreads();
        #pragma unroll
        for (int i = 0; i < APT; ++i) {
            int q2 = tid + TH * i;
            int r2 = q2 / NCH, ch = q2 % NCH;
            *(s16x8*)(sA + (r2 * NCH + (ch ^ (r2 & 7))) * 8) = ra[i];
        }
        #pragma unroll
        for (int i = 0; i < BPT; ++i) {
            int q2 = tid + TH * i;
            int r2 = q2 / NCH, ch = q2 % NCH;
            *(s16x8*)(sB + (r2 * NCH + (ch ^ (r2 & 7))) * 8) = rb[i];
        }
        __syncthreads();
        #pragma unroll
        for (int ks = 0; ks < BK / 32; ++ks) {
            s16x8 af[FM], bf[FN];
            #pragma unroll
            for (int fm = 0; fm < FM; ++fm) {
                int rr2 = wr * WM + fm * 16 + l15, cc = ks * 4 + l4;
                af[fm] = *(const s16x8*)&sA[(rr2 * NCH + (cc ^ (rr2 & 7))) * 8];
            }
            #pragma unroll
            for (int fn = 0; fn < FN; ++fn) {
                int rr2 = wc * WN + fn * 16 + l15, cc = ks * 4 + l4;
                bf[fn] = *(const s16x8*)&sB[(rr2 * NCH + (cc ^ (rr2 & 7))) * 8];
            }
            #pragma unroll
            for (int fm = 0; fm < FM; ++fm)
                #pragma unroll
                for (int fn = 0; fn < FN; ++fn)
                    acc[fm][fn] = __builtin_amdgcn_mfma_f32_16x16x32_bf16(af[fm], bf[fn], acc[fm][fn], 0, 0, 0);
        }
        __syncthreads();
    }
}

// ---------------------------------------------------------------------------
// Standalone GEMM (precompute + y + K1). B stored [N][K].
// EPI: 0 = bf16 out + bias, XCD-chunked 1-D grid (att1; 392 blocks)
//      1 = bf16 out, no bias (eprec)
//      3 = deferred y with mask (1-D XCD-chunked grid 157*19)
//      4 = K1: 1-D grid 160; n<512 -> att2b f32 (+dec_b);
//              else gatebuf sigmoid (+beta_b)
//      6 = h0c0: n<512 -> xin h-slot bf16 (+h_fc_b); else c_state (+c_fc_b)
// ---------------------------------------------------------------------------
template<int BM, int BN, int BK, int TH, int WR, int WC, int EPI>
__global__ __launch_bounds__(TH) void gemm_k(
    const short* __restrict__ Ag, int lda,
    const short* __restrict__ Bg, int ldb,
    int K,
    float* __restrict__ outF, float* __restrict__ outF2,
    short* __restrict__ outH, short* __restrict__ outH2,
    int ldo,
    const float* __restrict__ bias, const float* __restrict__ bias2,
    const int* __restrict__ lens)
{
    constexpr int NCH = BK / 8;
    constexpr int AU = NCH * BM, BU = NCH * BN;
    constexpr int APT = AU / TH, BPT = BU / TH;
    constexpr int WM = BM / WR, WN = BN / WC;
    constexpr int FM = WM / 16, FN = WN / 16;

    __shared__ __align__(16) short sA[AU * 8];
    __shared__ __align__(16) short sB[BU * 8];

    const int tid = threadIdx.x, lane = tid & 63, wid = tid >> 6;
    const int l15 = lane & 15, l4 = lane >> 4;

    int m0, n0, trow_ = 0;
    if constexpr (EPI == 0) {
        int task = (blockIdx.x & 7) * 49 + (blockIdx.x >> 3);   // 392 blocks
        m0 = (task >> 1) * BM;
        n0 = (task & 1) * BN;
    } else if constexpr (EPI == 3) {
        const int nwg = (int)gridDim.x;                         // 157*19
        const int qq = nwg >> 3, rr = nwg & 7;
        int xcd = (int)blockIdx.x & 7, idx = (int)blockIdx.x >> 3;
        int task = (xcd < rr) ? xcd * (qq + 1) + idx
                              : rr * (qq + 1) + (xcd - rr) * qq + idx;
        int npanel = task / Tt;
        trow_ = task - npanel * Tt;
        m0 = trow_ * BM;
        n0 = npanel * BN;
    } else if constexpr (EPI == 4) {
        m0 = ((int)blockIdx.x & 3) * BM;
        n0 = ((int)blockIdx.x >> 2) * BN;
    } else {
        m0 = blockIdx.y * BM;
        n0 = blockIdx.x * BN;
    }
    const int wr = wid / WC, wc = wid % WC;

    f32x4 acc[FM][FN];
    #pragma unroll
    for (int i = 0; i < FM; ++i)
        #pragma unroll
        for (int j = 0; j < FN; ++j) acc[i][j] = {0.f, 0.f, 0.f, 0.f};

    for (int kt = 0; kt < K; kt += BK) {
        s16x8 ra[APT], rb[BPT];
        #pragma unroll
        for (int i = 0; i < APT; ++i) {
            int q2 = tid + TH * i;
            int r2 = q2 / NCH, ch = q2 % NCH;
            ra[i] = *(const s16x8*)(Ag + (size_t)(m0 + r2) * lda + kt + ch * 8);
        }
        #pragma unroll
        for (int i = 0; i < BPT; ++i) {
            int q2 = tid + TH * i;
            int r2 = q2 / NCH, ch = q2 % NCH;
            rb[i] = *(const s16x8*)(Bg + (size_t)(n0 + r2) * ldb + kt + ch * 8);
        }
        __syncthreads();
        #pragma unroll
        for (int i = 0; i < APT; ++i) {
            int q2 = tid + TH * i;
            int r2 = q2 / NCH, ch = q2 % NCH;
            *(s16x8*)(sA + (r2 * NCH + (ch ^ (r2 & 7))) * 8) = ra[i];
        }
        #pragma unroll
        for (int i = 0; i < BPT; ++i) {
            int q2 = tid + TH * i;
            int r2 = q2 / NCH, ch = q2 % NCH;
            *(s16x8*)(sB + (r2 * NCH + (ch ^ (r2 & 7))) * 8) = rb[i];
        }
        __syncthreads();
        #pragma unroll
        for (int ks = 0; ks < BK / 32; ++ks) {
            s16x8 af[FM], bf[FN];
            #pragma unroll
            for (int fm = 0; fm < FM; ++fm) {
                int rr2 = wr * WM + fm * 16 + l15, cc = ks * 4 + l4;
                af[fm] = *(const s16x8*)&sA[(rr2 * NCH + (cc ^ (rr2 & 7))) * 8];
            }
            #pragma unroll
            for (int fn = 0; fn < FN; ++fn) {
                int rr2 = wc * WN + fn * 16 + l15, cc = ks * 4 + l4;
                bf[fn] = *(const s16x8*)&sB[(rr2 * NCH + (cc ^ (rr2 & 7))) * 8];
            }
            #pragma unroll
            for (int fm = 0; fm < FM; ++fm)
                #pragma unroll
                for (int fn = 0; fn < FN; ++fn)
                    acc[fm][fn] = __builtin_amdgcn_mfma_f32_16x16x32_bf16(af[fm], bf[fn], acc[fm][fn], 0, 0, 0);
        }
        __syncthreads();
    }

    #pragma unroll
    for (int fm = 0; fm < FM; ++fm)
        #pragma unroll
        for (int fn = 0; fn < FN; ++fn)
            #pragma unroll
            for (int r2 = 0; r2 < 4; ++r2) {
                int ml = wr * WM + fm * 16 + l4 * 4 + r2;
                int nl = wc * WN + fn * 16 + l15;
                int m = m0 + ml, n = n0 + nl;
                float v = acc[fm][fn][r2];
                if constexpr (EPI == 0) {
                    outH[(size_t)m * ldo + n] = bfs(v + bias[n]);
                } else if constexpr (EPI == 1) {
                    outH[(size_t)m * ldo + n] = bfs(v);
                } else if constexpr (EPI == 3) {
                    if (n < Vv) {
                        bool mk = trow_ < lens[ml] - 1;
                        outF[((size_t)ml * Tt + trow_) * Vv + n] = mk ? (v + bias[n]) : 0.f;
                    }
                } else if constexpr (EPI == 4) {
                    if (n < 512) outF[(size_t)m * Aa + n] = v + bias[n];
                    else outF2[(size_t)m * Dd + (n - 512)] =
                             1.f / (1.f + expf(-(v + bias2[n - 512])));
                } else if constexpr (EPI == 6) {
                    if (n < 512) {
                        outH2[(size_t)m * KXN + 2048 + n] = bfs(v + bias[n]);
                    } else {
                        outF2[(size_t)m * 512 + (n - 512)] = v + bias2[n - 512];
                    }
                }
            }
}

// ---------------------------------------------------------------------------
// K2: fused e = relu(att1+att2)@att_w + att_b -> softmax -> alpha -> awe.
// grid (2, 128), 512 threads. Each block: full e/softmax (redundant per half),
// half the awe d-range (1024 cols). alpha output written by half 0 only.
// ---------------------------------------------------------------------------
__global__ __launch_bounds__(512) void att_awe_k(
    const short* __restrict__ att1b, const float* __restrict__ att2b,
    const float* __restrict__ att_w, const float* __restrict__ att_b,
    const short* __restrict__ featb, const float* __restrict__ gatebuf,
    short* __restrict__ xin, float* __restrict__ al_out,
    const int* __restrict__ lens, int t)
{
    const int b = blockIdx.y, half = blockIdx.x;
    const int tid = threadIdx.x, lane = tid & 63, wid = tid >> 6;
    __shared__ float se[224];
    __shared__ float sred[256];
    __shared__ float sal[224];

    float aw[8], a2[8];
    #pragma unroll
    for (int j = 0; j < 8; ++j) {
        aw[j] = att_w[lane * 8 + j];
        a2[j] = att2b[b * 512 + lane * 8 + j];
    }
    float ab = att_b[0];
    for (int p = wid; p < Pp; p += 8) {
        s16x8 row = *(const s16x8*)&att1b[((size_t)b * Pp + p) * 512 + lane * 8];
        float s = 0.f;
        #pragma unroll
        for (int j = 0; j < 8; ++j) {
            float v = fbs(row[j]) + a2[j];
            v = v > 0.f ? v : 0.f;
            s += v * aw[j];
        }
        #pragma unroll
        for (int m = 32; m; m >>= 1) s += __shfl_xor(s, m);
        if (lane == 0) se[p] = s + ab;
    }
    __syncthreads();
    float e = 0.f, ex = 0.f;
    if (tid < 256) {
        e = (tid < Pp) ? se[tid] : -3.0e38f;
        sred[tid] = e;
    }
    __syncthreads();
    for (int st = 128; st > 0; st >>= 1) {
        if (tid < st) sred[tid] = fmaxf(sred[tid], sred[tid + st]);
        __syncthreads();
    }
    float mx = sred[0];
    __syncthreads();
    if (tid < 256) {
        ex = (tid < Pp) ? expf(e - mx) : 0.f;
        sred[tid] = ex;
    }
    __syncthreads();
    for (int st = 128; st > 0; st >>= 1) {
        if (tid < st) sred[tid] += sred[tid + st];
        __syncthreads();
    }
    float inv = 1.f / sred[0];
    if (tid < Pp) {
        float al = ex * inv;
        sal[tid] = al;
        if (half == 0) {
            float mf = (t < lens[b] - 1) ? 1.f : 0.f;
            al_out[((size_t)b * Tt + t) * Pp + tid] = al * mf;
        }
    }
    __syncthreads();
    // awe over this half's 1024 cols
    int d0 = half * 1024 + tid * 2;
    const short* f = featb + (size_t)b * Pp * Dd + d0;
    float s0 = 0.f, s1 = 0.f;
    #pragma unroll 4
    for (int p = 0; p < Pp; ++p) {
        uint32_t v = *(const uint32_t*)(f + (size_t)p * Dd);
        float al = sal[p];
        s0 += al * fbs((short)(v & 0xFFFF));
        s1 += al * fbs((short)(v >> 16));
    }
    float2 g = *(const float2*)&gatebuf[b * 2048 + d0];
    uint32_t o = ((uint32_t)(uint16_t)bfs(g.y * s1) << 16) | (uint16_t)bfs(g.x * s0);
    *(uint32_t*)(xin + (size_t)b * KXN + d0) = o;
}

// ---------------------------------------------------------------------------
// K3: gates = xin @ combT (quad-permuted) + eprec + biases -> LSTM update.
// grid 256 (1-D): m0 = (bid&3)*32, n0 = (bid>>2)*32. K = 2560.
// ---------------------------------------------------------------------------
__global__ __launch_bounds__(256) void gates_lstm_k(
    const short* __restrict__ xin, const short* __restrict__ combT,
    const short* __restrict__ eprec,
    const float* __restrict__ b_ih, const float* __restrict__ b_hh,
    float* __restrict__ c_state, short* __restrict__ hnew_all,
    short* __restrict__ xin_h, const int* __restrict__ lens, int t)
{
    __shared__ __align__(16) char smem[16384];
    int m0 = ((int)blockIdx.x & 3) * 32, n0 = ((int)blockIdx.x >> 2) * 32;
    f32x4 acc[1][1];
    tile_mm<32, 32, 128, 2, 2>(xin, KXN, combT, KXN, KXN, m0, n0, smem, acc);
    int tid = threadIdx.x, lane = tid & 63, wid = tid >> 6;
    int l15 = lane & 15, l4 = lane >> 4, wr = wid / 2, wc = wid % 2;
    float* sE = (float*)smem;
    #pragma unroll
    for (int r = 0; r < 4; ++r) {
        int ml = wr * 16 + l4 * 4 + r, nl = wc * 16 + l15;
        sE[ml * 32 + nl] = acc[0][0][r];
    }
    __syncthreads();
    int bl = tid >> 3, jl = tid & 7;
    int b = m0 + bl, q = (n0 >> 2) + jl;
    f32x4 ge = *(const f32x4*)&sE[bl * 32 + jl * 4];
    short4 ep = *(const short4*)&eprec[((size_t)t * 128 + b) * 2048 + n0 + jl * 4];
    float gi = ge[0] + fbs(ep.x) + b_ih[q]        + b_hh[q];
    float gf = ge[1] + fbs(ep.y) + b_ih[512 + q]  + b_hh[512 + q];
    float gg = ge[2] + fbs(ep.z) + b_ih[1024 + q] + b_hh[1024 + q];
    float go = ge[3] + fbs(ep.w) + b_ih[1536 + q] + b_hh[1536 + q];
    float si = 1.f / (1.f + expf(-gi));
    float sf = 1.f / (1.f + expf(-gf));
    float so = 1.f / (1.f + expf(-go));
    float tg = tanhf(gg);
    int sidx = b * 512 + q;
    float cn = sf * c_state[sidx] + si * tg;
    float hn = so * tanhf(cn);
    hnew_all[((size_t)t * 128 + b) * 512 + q] = bfs(hn);
    if (t < lens[b] - 1) {
        c_state[sidx] = cn;
        xin_h[(size_t)b * KXN + 2048 + q] = bfs(hn);
    }
}

// ---------------------------------------------------------------------------
__global__ __launch_bounds__(256) void conv_mean_k(
    const float* __restrict__ feat, short* __restrict__ featb, short* __restrict__ meanb)
{
    int b = blockIdx.y;
    int d = (blockIdx.x * 256 + threadIdx.x) * 4;
    const float* f = feat + (size_t)b * Pp * Dd + d;
    short* o = featb + (size_t)b * Pp * Dd + d;
    float s0 = 0.f, s1 = 0.f, s2 = 0.f, s3 = 0.f;
    for (int p = 0; p < Pp; ++p) {
        float4 v = *(const float4*)(f + (size_t)p * Dd);
        s0 += v.x; s1 += v.y; s2 += v.z; s3 += v.w;
        short4 ov = make_short4(bfs(v.x), bfs(v.y), bfs(v.z), bfs(v.w));
        *(short4*)(o + (size_t)p * Dd) = ov;
    }
    const float inv = 1.f / 196.f;
    short4 mv = make_short4(bfs(s0 * inv), bfs(s1 * inv), bfs(s2 * inv), bfs(s3 * inv));
    *(short4*)(meanb + (size_t)b * Dd + d) = mv;
}

// fp32 [R][C] -> bf16 [perm(c)][dstStride] transpose (+zero pad).
// PERM=1: dst row = (c%512)*4 + c/512 (quad-permuted gate layout, C==2048).
template<int PERM>
__global__ __launch_bounds__(256) void transpose_bf16(
    const float* __restrict__ src, int R, int C,
    short* __restrict__ dst, int dstStride, int colOff, int Cpad)
{
    __shared__ float tile[32][33];
    int c0 = blockIdx.x * 32, r0 = blockIdx.y * 32;
    int tx = threadIdx.x & 31, ty = threadIdx.x >> 5;
    #pragma unroll
    for (int i = 0; i < 4; ++i) {
        int r = r0 + ty + i * 8, c = c0 + tx;
        tile[ty + i * 8][tx] = (r < R && c < C) ? src[(size_t)r * C + c] : 0.f;
    }
    __syncthreads();
    #pragma unroll
    for (int i = 0; i < 4; ++i) {
        int cc = c0 + ty + i * 8, rr = r0 + tx;
        if (cc < Cpad && rr < R) {
            int drow = PERM ? ((cc & 511) * 4 + (cc >> 9)) : cc;
            dst[(size_t)drow * dstStride + colOff + rr] = bfs(tile[tx][ty + i * 8]);
        }
    }
}

__global__ __launch_bounds__(256) void embg_k(
    const float* __restrict__ emb, const int* __restrict__ caps, short* __restrict__ embseq)
{
    size_t i = (size_t)blockIdx.x * 256 + threadIdx.x;
    if (i >= (size_t)Tt * Bb * Ee) return;
    int e = (int)(i % Ee);
    size_t r = i / Ee;
    int b = (int)(r % Bb);
    int t = (int)(r / Bb);
    int cap = caps[b * TMAX + t];
    embseq[i] = bfs(emb[(size_t)cap * Ee + e]);
}

// ---------------------------------------------------------------------------
extern "C" void kernel_launch(void* const* d_in, const int* in_sizes, int n_in,
                              void* d_out, int out_size, void* d_ws, size_t ws_size,
                              hipStream_t stream)
{
    const float* features = (const float*)d_in[0];
    const int* captions   = (const int*)d_in[1];
    const int* lengths    = (const int*)d_in[2];
    const float* emb      = (const float*)d_in[3];
    const float* h_fc_w   = (const float*)d_in[4];
    const float* h_fc_b   = (const float*)d_in[5];
    const float* c_fc_w   = (const float*)d_in[6];
    const float* c_fc_b   = (const float*)d_in[7];
    const float* enc_w    = (const float*)d_in[8];
    const float* enc_b    = (const float*)d_in[9];
    const float* dec_w    = (const float*)d_in[10];
    const float* dec_b    = (const float*)d_in[11];
    const float* att_w    = (const float*)d_in[12];
    const float* att_b    = (const float*)d_in[13];
    const float* beta_w   = (const float*)d_in[14];
    const float* beta_b   = (const float*)d_in[15];
    const float* w_ih     = (const float*)d_in[16];
    const float* b_ih     = (const float*)d_in[17];
    const float* w_hh     = (const float*)d_in[18];
    const float* b_hh     = (const float*)d_in[19];
    const float* cls_w    = (const float*)d_in[20];
    const float* cls_b    = (const float*)d_in[21];

    char* w = (char*)d_ws;
    auto alloc = [&](size_t bytes) {
        char* p = w;
        w += (bytes + 255) & ~(size_t)255;
        return p;
    };
    short* featb    = (short*)alloc((size_t)Bb * Pp * Dd * 2);
    short* att1b    = (short*)alloc((size_t)Bb * Pp * Aa * 2);
    short* encT     = (short*)alloc((size_t)Aa * Dd * 2);
    short* combT    = (short*)alloc((size_t)2048 * KXN * 2);   // quad-perm rows
    short* wtopT    = (short*)alloc((size_t)2048 * 512 * 2);   // quad-perm rows
    short* clsT     = (short*)alloc((size_t)NVP * Hh * 2);
    short* catT     = (short*)alloc((size_t)2560 * Hh * 2);    // [dec;beta]
    short* hcT      = (short*)alloc((size_t)1024 * Dd * 2);    // [h_fc;c_fc]
    short* embseq   = (short*)alloc((size_t)Tt * Bb * Ee * 2);
    short* meanb    = (short*)alloc((size_t)Bb * Dd * 2);
    short* eprec    = (short*)alloc((size_t)Tt * Bb * 2048 * 2);
    float* c_state  = (float*)alloc((size_t)Bb * Hh * 4);
    float* att2b    = (float*)alloc((size_t)Bb * Aa * 4);
    float* gatebuf  = (float*)alloc((size_t)Bb * Dd * 4);
    short* xin      = (short*)alloc((size_t)Bb * KXN * 2);
    short* hnew_all = (short*)alloc((size_t)Tt * Bb * Hh * 2);

    float* y_out  = (float*)d_out;
    float* al_out = y_out + (size_t)Bb * Tt * Vv;

    // ---- precompute ----
    conv_mean_k<<<dim3(2, 128), 256, 0, stream>>>(features, featb, meanb);
    transpose_bf16<0><<<dim3(16, 64), 256, 0, stream>>>(enc_w, 2048, 512, encT, 2048, 0, 512);
    transpose_bf16<0><<<dim3(16, 64), 256, 0, stream>>>(h_fc_w, 2048, 512, hcT, 2048, 0, 512);
    transpose_bf16<0><<<dim3(16, 64), 256, 0, stream>>>(c_fc_w, 2048, 512, hcT + (size_t)512 * 2048, 2048, 0, 512);
    transpose_bf16<0><<<dim3(16, 16), 256, 0, stream>>>(dec_w, 512, 512, catT, 512, 0, 512);
    transpose_bf16<0><<<dim3(64, 16), 256, 0, stream>>>(beta_w, 512, 2048, catT + (size_t)512 * 512, 512, 0, 2048);
    transpose_bf16<1><<<dim3(64, 64), 256, 0, stream>>>(w_ih + (size_t)512 * 2048, 2048, 2048, combT, KXN, 0, 2048);
    transpose_bf16<1><<<dim3(64, 16), 256, 0, stream>>>(w_hh, 512, 2048, combT, KXN, 2048, 2048);
    transpose_bf16<1><<<dim3(64, 16), 256, 0, stream>>>(w_ih, 512, 2048, wtopT, 512, 0, 2048);
    transpose_bf16<0><<<dim3(314, 16), 256, 0, stream>>>(cls_w, 512, 10000, clsT, 512, 0, NVP);
    embg_k<<<(Tt * Bb * Ee + 255) / 256, 256, 0, stream>>>(emb, captions, embseq);

    // h0/c0 GEMM: meanb @ hcT^T (EPI 6) -> xin h-slot + c_state
    gemm_k<128, 64, 64, 256, 2, 2, 6><<<dim3(16, 1), 256, 0, stream>>>(
        meanb, 2048, hcT, 2048, 2048,
        nullptr, c_state, nullptr, xin, 0, h_fc_b, c_fc_b, nullptr);

    // att1 = features @ enc_w + enc_b (bf16), XCD-chunked 392-block grid
    gemm_k<128, 256, 64, 512, 2, 4, 0><<<dim3(392), 512, 0, stream>>>(
        featb, 2048, encT, 2048, 2048,
        nullptr, nullptr, att1b, nullptr, Aa, enc_b, nullptr, nullptr);

    // eprec = embseq @ wtopT^T (bf16, quad-permuted cols), all 19 steps
    gemm_k<128, 64, 64, 256, 2, 2, 1><<<dim3(32, 19), 256, 0, stream>>>(
        embseq, 512, wtopT, 512, 512,
        nullptr, nullptr, eprec, nullptr, 2048, nullptr, nullptr, nullptr);

    // ---- decode steps: 3 launches each ----
    for (int t = 0; t < Tt; ++t) {
        // K1: att2 (f32 +dec_b) + gate (sigmoid +beta_b): h @ catT, 160 blocks
        gemm_k<32, 64, 64, 256, 2, 2, 4><<<dim3(160), 256, 0, stream>>>(
            xin + 2048, KXN, catT, 512, 512,
            att2b, gatebuf, nullptr, nullptr, 0, dec_b, beta_b, nullptr);
        // K2: fused e/softmax/awe -> xin awe-slot (+alpha output)
        att_awe_k<<<dim3(2, 128), 512, 0, stream>>>(
            att1b, att2b, att_w, att_b, featb, gatebuf, xin,
            al_out, lengths, t);
        // K3: gates GEMM (K=2560) + fused LSTM -> c_state, hnew_all, xin h-slot
        gates_lstm_k<<<dim3(256), 256, 0, stream>>>(
            xin, combT, eprec, b_ih, b_hh, c_state, hnew_all, xin, lengths, t);
    }

    // deferred y: hnew_all[2432][512] @ clsT^T, XCD-chunked
    gemm_k<128, 64, 64, 256, 2, 2, 3><<<dim3(157 * Tt), 256, 0, stream>>>(
        hnew_all, 512, clsT, 512, 512,
        y_out, nullptr, nullptr, nullptr, 0, cls_b, nullptr, lengths);
}